// Round 14
// baseline (205.675 us; speedup 1.0000x reference)
//
#include <hip/hip_runtime.h>
#include <math.h>

#define BB      2
#define CC      512
#define NN_TOK  4096
#define HEADS   8
#define DHEAD   64
#define HID     512
#define GROUPS  32
#define CPG     (CC / GROUPS)
#define EPS     1e-5f

typedef __bf16 bf16x8 __attribute__((ext_vector_type(8)));
typedef float  f32x4  __attribute__((ext_vector_type(4)));
typedef float  f32x16 __attribute__((ext_vector_type(16)));

static __device__ __forceinline__ unsigned short f2bf(float f) {
  __bf16 h = (__bf16)f;
  return __builtin_bit_cast(unsigned short, h);
}
static __device__ __forceinline__ float bf2f(unsigned short u) {
  unsigned v = (unsigned)u << 16;
  return __builtin_bit_cast(float, v);
}
static __device__ __forceinline__ unsigned pk_fp8x4(float a, float b, float c, float d) {
  int lo = __builtin_amdgcn_cvt_pk_fp8_f32(a, b, 0, false);
  return (unsigned)__builtin_amdgcn_cvt_pk_fp8_f32(c, d, lo, true);
}
static __device__ __forceinline__ unsigned char f2fp8(float a) {
  return (unsigned char)(__builtin_amdgcn_cvt_pk_fp8_f32(a, a, 0, false) & 0xff);
}
static __device__ __forceinline__ long mklong(unsigned lo, unsigned hi) {
  return (long)(((unsigned long long)hi << 32) | lo);
}
#define WSCALE 16.0f        // wo pre-scale before fp8 (dodges e4m3 subnormals)
#define WSCALE_INV 0.0625f

// ---------------------------------------------------------------------------
// GroupNorm stats (one block per quarter-group, grid 256) + fused weight
// conversion: blocks 0..191 convert wq/wk/wv -> bf16; 192..255 convert
// wo*16 -> fp8.
// ---------------------------------------------------------------------------
__global__ __launch_bounds__(256) void gn_stats_wconv_kernel(
    const float* __restrict__ x, float2* __restrict__ part,
    const float* __restrict__ wq, const float* __restrict__ wk,
    const float* __restrict__ wv, const float* __restrict__ wo,
    unsigned short* __restrict__ wqb, unsigned short* __restrict__ wkb,
    unsigned short* __restrict__ wvb, unsigned char* __restrict__ wo8) {
  int blk = blockIdx.x;
  int t = threadIdx.x;
  // --- weight conversion slice: 4096 elements per block, 16 per thread ---
  {
    int base = blk * 4096 + t * 16;
    if (blk < 192) {
      int wsel = base >> 18;             // 262144 elements per weight
      int off = base & 262143;
      const float* s = (wsel == 0) ? wq : (wsel == 1) ? wk : wv;
      unsigned short* d = (wsel == 0) ? wqb : (wsel == 1) ? wkb : wvb;
      #pragma unroll
      for (int i = 0; i < 4; ++i) {
        float4 a = *(const float4*)&s[off + i * 4];
        ushort4 p;
        p.x = f2bf(a.x); p.y = f2bf(a.y); p.z = f2bf(a.z); p.w = f2bf(a.w);
        *(ushort4*)&d[off + i * 4] = p;
      }
    } else {
      int off = base - 786432;
      #pragma unroll
      for (int i = 0; i < 4; ++i) {
        float4 a = *(const float4*)&wo[off + i * 4];
        *(unsigned*)&wo8[off + i * 4] =
            pk_fp8x4(a.x * WSCALE, a.y * WSCALE, a.z * WSCALE, a.w * WSCALE);
      }
    }
  }
  // --- stats ---
  const float4* __restrict__ x4 = (const float4*)(x + (size_t)blk * 16384);
  float s = 0.f, ss = 0.f;
  #pragma unroll
  for (int i = 0; i < 16; ++i) {
    float4 v = x4[t + i * 256];
    s  += v.x + v.y + v.z + v.w;
    ss += v.x * v.x + v.y * v.y + v.z * v.z + v.w * v.w;
  }
  #pragma unroll
  for (int off = 32; off >= 1; off >>= 1) {
    s  += __shfl_down(s, off, 64);
    ss += __shfl_down(ss, off, 64);
  }
  __shared__ float rs[4], rss[4];
  int wid = t >> 6, lane = t & 63;
  if (lane == 0) { rs[wid] = s; rss[wid] = ss; }
  __syncthreads();
  if (t == 0) {
    float2 o;
    o.x = rs[0] + rs[1] + rs[2] + rs[3];
    o.y = rss[0] + rss[1] + rss[2] + rss[3];
    part[blk] = o;
  }
}

// ---------------------------------------------------------------------------
// Fused GroupNorm-apply + transpose: x fp32 [b][c][tok] -> xnT bf16 [b][tok][c].
// ---------------------------------------------------------------------------
__global__ __launch_bounds__(256) void gn_norm_t_kernel(
    const float* __restrict__ x, const float* __restrict__ gamma,
    const float* __restrict__ beta, const float2* __restrict__ part,
    unsigned short* __restrict__ xnT) {
  __shared__ __align__(16) unsigned short lds[64 * 72];
  __shared__ float mu4[4], rs4[4];
  int b = blockIdx.z;
  int t0 = blockIdx.x * 64, c0 = blockIdx.y * 64;
  int t = threadIdx.x;
  if (t < 4) {
    int g = (c0 >> 4) + t;
    int gi = b * GROUPS + g;
    float2 p0 = part[gi * 4 + 0], p1 = part[gi * 4 + 1];
    float2 p2 = part[gi * 4 + 2], p3 = part[gi * 4 + 3];
    float S = p0.x + p1.x + p2.x + p3.x;
    float SS = p0.y + p1.y + p2.y + p3.y;
    const float inv_n = 1.0f / (float)(CPG * NN_TOK);
    float mu = S * inv_n;
    float var = SS * inv_n - mu * mu;
    mu4[t] = mu;
    rs4[t] = rsqrtf(var + EPS);
  }
  __syncthreads();
  const float* __restrict__ xb = x + (size_t)b * CC * NN_TOK;
  #pragma unroll
  for (int i = 0; i < 4; ++i) {
    int f = t + i * 256;
    int row = f >> 4, c16 = f & 15;
    int c = c0 + row;
    float ga = gamma[c] * rs4[row >> 4];
    float be = beta[c] - mu4[row >> 4] * ga;
    float4 v = *(const float4*)&xb[(size_t)c * NN_TOK + t0 + c16 * 4];
    ushort4 pk;
    pk.x = f2bf(v.x * ga + be); pk.y = f2bf(v.y * ga + be);
    pk.z = f2bf(v.z * ga + be); pk.w = f2bf(v.w * ga + be);
    *(ushort4*)&lds[row * 72 + c16 * 4] = pk;
  }
  __syncthreads();
  unsigned short* __restrict__ ob = xnT + (size_t)b * NN_TOK * CC;
  #pragma unroll
  for (int i = 0; i < 2; ++i) {
    int f = t + i * 256;
    int row = f >> 3, ch = f & 7;
    ushort4 a, b4;
    a.x  = lds[(ch * 8 + 0) * 72 + row];
    a.y  = lds[(ch * 8 + 1) * 72 + row];
    a.z  = lds[(ch * 8 + 2) * 72 + row];
    a.w  = lds[(ch * 8 + 3) * 72 + row];
    b4.x = lds[(ch * 8 + 4) * 72 + row];
    b4.y = lds[(ch * 8 + 5) * 72 + row];
    b4.z = lds[(ch * 8 + 6) * 72 + row];
    b4.w = lds[(ch * 8 + 7) * 72 + row];
    *(ushort4*)&ob[(size_t)(t0 + row) * CC + c0 + ch * 8] = a;
    *(ushort4*)&ob[(size_t)(t0 + row) * CC + c0 + ch * 8 + 4] = b4;
  }
}

// ---------------------------------------------------------------------------
// Fused Q/K/V MFMA GEMM -> fp8 outputs (r13, proven).
// ---------------------------------------------------------------------------
__global__ __launch_bounds__(256, 3) void qkv_gemm_kernel(
    const unsigned short* __restrict__ xnT,
    const unsigned short* __restrict__ wqb, const unsigned short* __restrict__ wkb,
    const unsigned short* __restrict__ wvb,
    const float* __restrict__ bq, const float* __restrict__ bk,
    const float* __restrict__ bv,
    unsigned char* __restrict__ qT8, unsigned char* __restrict__ kT8,
    unsigned char* __restrict__ vB8) {
  __shared__ __align__(16) unsigned short AsBs[2 * 128 * 72];
  unsigned short* As = AsBs;
  unsigned short* Bs = AsBs + 128 * 72;
  int b = blockIdx.z;
  int y = blockIdx.y;
  int which = y >> 2, yl = y & 3;
  const unsigned short* __restrict__ W =
      (which == 0) ? wqb : (which == 1) ? wkb : wvb;
  const float* __restrict__ bias = (which == 0) ? bq : (which == 1) ? bk : bv;
  int m0 = yl * 128;
  int n0 = blockIdx.x * 128;
  const unsigned short* __restrict__ Bsrc = xnT + (size_t)b * NN_TOK * CC;
  int t = threadIdx.x, w = t >> 6, lane = t & 63;
  int wm = (w >> 1) * 64, wn = (w & 1) * 64;
  int l15 = lane & 15, lq = lane >> 4;

  f32x4 acc[4][4];
  #pragma unroll
  for (int mt = 0; mt < 4; ++mt)
    #pragma unroll
    for (int nt = 0; nt < 4; ++nt) acc[mt][nt] = (f32x4){0.f, 0.f, 0.f, 0.f};

  for (int kc = 0; kc < CC; kc += 64) {
    __syncthreads();
    #pragma unroll
    for (int i = 0; i < 4; ++i) {
      int f = t + i * 256;
      int row = f >> 3, ch = f & 7;
      *(uint4*)&As[row * 72 + ch * 8] =
          *(const uint4*)&W[(size_t)(m0 + row) * CC + kc + ch * 8];
      *(uint4*)&Bs[row * 72 + ch * 8] =
          *(const uint4*)&Bsrc[(size_t)(n0 + row) * CC + kc + ch * 8];
    }
    __syncthreads();
    #pragma unroll
    for (int ks = 0; ks < 2; ++ks) {
      bf16x8 af[4], bfr[4];
      #pragma unroll
      for (int i = 0; i < 4; ++i) {
        af[i]  = *(const bf16x8*)&As[(wm + i * 16 + l15) * 72 + ks * 32 + lq * 8];
        bfr[i] = *(const bf16x8*)&Bs[(wn + i * 16 + l15) * 72 + ks * 32 + lq * 8];
      }
      #pragma unroll
      for (int mt = 0; mt < 4; ++mt)
        #pragma unroll
        for (int nt = 0; nt < 4; ++nt)
          acc[mt][nt] = __builtin_amdgcn_mfma_f32_16x16x32_bf16(
              af[mt], bfr[nt], acc[mt][nt], 0, 0, 0);
    }
  }
  __syncthreads();

  if (which < 2) {
    const float sc = (which == 0) ? 0.18033688011112043f : 1.0f; // 0.125*log2e
    unsigned char* __restrict__ dstT = (which == 0) ? qT8 : kT8;
    unsigned char* buf = (unsigned char*)AsBs + w * 2560;  // per-wave [32 tok][80 B]
    int h = (m0 + wm) >> 6;
    const size_t hbase = (size_t)(b * HEADS + h) * NN_TOK;
    #pragma unroll
    for (int p = 0; p < 2; ++p) {
      #pragma unroll
      for (int mt = 0; mt < 4; ++mt) {
        float4 bv4 = *(const float4*)&bias[m0 + wm + mt * 16 + lq * 4];
        #pragma unroll
        for (int ntl = 0; ntl < 2; ++ntl) {
          int nt = p * 2 + ntl;
          f32x4 a = acc[mt][nt];
          unsigned pk = pk_fp8x4((a[0] + bv4.x) * sc, (a[1] + bv4.y) * sc,
                                 (a[2] + bv4.z) * sc, (a[3] + bv4.w) * sc);
          *(unsigned*)&buf[(ntl * 16 + l15) * 80 + mt * 16 + lq * 4] = pk;
        }
      }
      #pragma unroll
      for (int it = 0; it < 2; ++it) {
        int idx = it * 64 + lane;
        int row = idx >> 2, ch = idx & 3;
        int tok = n0 + wn + p * 32 + row;
        *(uint4*)&dstT[(hbase + tok) * DHEAD + ch * 16] =
            *(const uint4*)&buf[row * 80 + ch * 16];
      }
      __syncthreads();
    }
  } else {
    unsigned char* __restrict__ dst = vB8 + (size_t)b * HID * NN_TOK;
    #pragma unroll
    for (int mt = 0; mt < 4; ++mt) {
      float4 bv4 = *(const float4*)&bias[m0 + wm + mt * 16 + lq * 4];
      float bvr[4] = {bv4.x, bv4.y, bv4.z, bv4.w};
      #pragma unroll
      for (int nt = 0; nt < 4; ++nt) {
        int tok = n0 + wn + nt * 16 + l15;
        #pragma unroll
        for (int r = 0; r < 4; ++r) {
          int m = m0 + wm + mt * 16 + lq * 4 + r;
          dst[(size_t)m * NN_TOK + tok] = f2fp8(acc[mt][nt][r] + bvr[r]);
        }
      }
    }
  }
}

// ---------------------------------------------------------------------------
// Out-proj MFMA GEMM, fp8 inputs (wo8 pre-scaled x16, aoT8 fp8).
// 128m x 64n, grid (64,4,2).
// ---------------------------------------------------------------------------
__global__ __launch_bounds__(256) void outproj_kernel(
    const unsigned char* __restrict__ aoT8, const unsigned char* __restrict__ wo8,
    const float* __restrict__ bo, const float* __restrict__ x,
    float* __restrict__ out) {
  __shared__ __align__(16) unsigned char As8[128 * 80];
  __shared__ __align__(16) unsigned char Bs8[64 * 80];
  int b = blockIdx.z;
  int m0 = blockIdx.y * 128;
  int n0 = blockIdx.x * 64;
  const unsigned char* __restrict__ Bsrc = aoT8 + (size_t)b * NN_TOK * HID;
  int t = threadIdx.x, w = t >> 6, lane = t & 63;
  int wm = (w & 1) * 64, wn = (w >> 1) * 32;
  int l15 = lane & 15, lq = lane >> 4;

  f32x4 acc[4][2];
  #pragma unroll
  for (int mt = 0; mt < 4; ++mt)
    #pragma unroll
    for (int nt = 0; nt < 2; ++nt) acc[mt][nt] = (f32x4){0.f, 0.f, 0.f, 0.f};

  for (int kc = 0; kc < HID; kc += 64) {
    __syncthreads();
    #pragma unroll
    for (int i = 0; i < 2; ++i) {
      int f = t + i * 256;
      int row = f >> 2, ch = f & 3;
      *(uint4*)&As8[row * 80 + ch * 16] =
          *(const uint4*)&wo8[(size_t)(m0 + row) * HID + kc + ch * 16];
    }
    {
      int row = t >> 2, ch = t & 3;
      *(uint4*)&Bs8[row * 80 + ch * 16] =
          *(const uint4*)&Bsrc[(size_t)(n0 + row) * HID + kc + ch * 16];
    }
    __syncthreads();
    #pragma unroll
    for (int ks = 0; ks < 2; ++ks) {
      long af[4], bfr[2];
      #pragma unroll
      for (int i = 0; i < 4; ++i)
        af[i] = *(const long*)&As8[(wm + i * 16 + l15) * 80 + ks * 32 + lq * 8];
      #pragma unroll
      for (int i = 0; i < 2; ++i)
        bfr[i] = *(const long*)&Bs8[(wn + i * 16 + l15) * 80 + ks * 32 + lq * 8];
      #pragma unroll
      for (int mt = 0; mt < 4; ++mt)
        #pragma unroll
        for (int nt = 0; nt < 2; ++nt)
          acc[mt][nt] = __builtin_amdgcn_mfma_f32_16x16x32_fp8_fp8(
              af[mt], bfr[nt], acc[mt][nt], 0, 0, 0);
    }
  }

  const float* __restrict__ xb = x + (size_t)b * CC * NN_TOK;
  float* __restrict__ ob = out + (size_t)b * CC * NN_TOK;
  #pragma unroll
  for (int mt = 0; mt < 4; ++mt) {
    float4 bv4 = *(const float4*)&bo[m0 + wm + mt * 16 + lq * 4];
    float bvr[4] = {bv4.x, bv4.y, bv4.z, bv4.w};
    #pragma unroll
    for (int nt = 0; nt < 2; ++nt) {
      int tok = n0 + wn + nt * 16 + l15;
      #pragma unroll
      for (int r = 0; r < 4; ++r) {
        int m = m0 + wm + mt * 16 + lq * 4 + r;
        size_t off = (size_t)m * NN_TOK + tok;
        ob[off] = acc[mt][nt][r] * WSCALE_INV + bvr[r] + xb[off];
      }
    }
  }
}

// ---------------------------------------------------------------------------
// MFMA flash attention, round 14: r13 fp8 core, j-SPLIT across blocks.
// grid (32, 32): blockIdx.y = bh*2 + jhalf; each block does 16 iters (2048 j)
// of its 128-i tile. Same compute:staging ratio as r13 but 1024 blocks ->
// 4 blocks/CU (LDS ~29 KB, VGPR ~52). Writes bf16 O-partials + l to ws;
// attn_combine adds halves, divides, emits fp8 aoT.
// ---------------------------------------------------------------------------
__global__ __launch_bounds__(512, 4) void attn_mfma_kernel(
    const unsigned char* __restrict__ qT8, const unsigned char* __restrict__ kT8,
    const unsigned char* __restrict__ vv8,
    unsigned short* __restrict__ Pp, float* __restrict__ Lp) {
  __shared__ __align__(16) unsigned char kvs[4 * 4608];   // 2 K + 2 V fp8 tiles
  __shared__ __align__(16) unsigned short st[4 * 2304];   // epilogue stage (bf16)
  __shared__ float lbuf[128];
  unsigned char* ks8 = kvs;
  unsigned char* vs8 = kvs + 2 * 4608;
  int by = blockIdx.y;
  int bh = by >> 1, jhalf = by & 1;
  int i0 = blockIdx.x * 128;
  const size_t hb = (size_t)bh * NN_TOK;
  const unsigned char* __restrict__ qtg = qT8 + hb * DHEAD;
  const unsigned char* __restrict__ ktg = kT8 + hb * DHEAD;
  const unsigned char* __restrict__ vg  = vv8 + hb * DHEAD;
  int t = threadIdx.x;
  int w = t >> 6, lane = t & 63, l31 = lane & 31, q1h = lane >> 5;
  int strip = w & 3, parity = w >> 2;
  int iw = i0 + strip * 32;

  const unsigned char* qrow = qtg + (size_t)(iw + l31) * DHEAD;
  uint4 qv0 = *(const uint4*)(qrow);
  uint4 qv1 = *(const uint4*)(qrow + 16);
  uint4 qv2 = *(const uint4*)(qrow + 32);
  uint4 qv3 = *(const uint4*)(qrow + 48);
  long qf[4];
  qf[0] = q1h ? mklong(qv0.z, qv0.w) : mklong(qv0.x, qv0.y);
  qf[1] = q1h ? mklong(qv1.z, qv1.w) : mklong(qv1.x, qv1.y);
  qf[2] = q1h ? mklong(qv2.z, qv2.w) : mklong(qv2.x, qv2.y);
  qf[3] = q1h ? mklong(qv3.z, qv3.w) : mklong(qv3.x, qv3.y);

  f32x16 o0 = {0,0,0,0,0,0,0,0,0,0,0,0,0,0,0,0};
  f32x16 o1 = {0,0,0,0,0,0,0,0,0,0,0,0,0,0,0,0};
  float lrun = 0.f;
  const unsigned char* __restrict__ ksw = ks8 + parity * 4608;
  const unsigned char* __restrict__ vsw = vs8 + parity * 4608;

  for (int rt = jhalf * 16; rt < jhalf * 16 + 16; ++rt) {
    int j0 = rt * 128;
    __syncthreads();
    {
      int jr = t >> 2, ch = t & 3;
      int ktile = jr >> 6, krow = jr & 63;
      uint4 kx = *(const uint4*)&ktg[(size_t)(j0 + jr) * DHEAD + ch * 16];
      unsigned char* kd = &ks8[ktile * 4608 + krow * 72 + ch * 16];
      *(uint2*)kd = make_uint2(kx.x, kx.y);
      *(uint2*)(kd + 8) = make_uint2(kx.z, kx.w);
      int vtile = t >> 8, vrr = (t >> 2) & 63, vch = t & 3;
      uint4 vx = *(const uint4*)&vg[(size_t)vrr * NN_TOK + j0 + vtile * 64 + vch * 16];
      unsigned char* vd = &vs8[vtile * 4608 + vrr * 72 + vch * 16];
      *(uint2*)vd = make_uint2(vx.x, vx.y);
      *(uint2*)(vd + 8) = make_uint2(vx.z, vx.w);
    }
    __syncthreads();

    f32x16 s0 = {0,0,0,0,0,0,0,0,0,0,0,0,0,0,0,0};
    f32x16 s1 = {0,0,0,0,0,0,0,0,0,0,0,0,0,0,0,0};
    #pragma unroll
    for (int s = 0; s < 4; ++s) {
      long a0 = *(const long*)&ksw[l31 * 72 + s * 16 + q1h * 8];
      long a1 = *(const long*)&ksw[(32 + l31) * 72 + s * 16 + q1h * 8];
      s0 = __builtin_amdgcn_mfma_f32_32x32x16_fp8_fp8(a0, qf[s], s0, 0, 0, 0);
      s1 = __builtin_amdgcn_mfma_f32_32x32x16_fp8_fp8(a1, qf[s], s1, 0, 0, 0);
    }

    unsigned pk4[8];
    float psum = 0.f;
    #pragma unroll
    for (int g = 0; g < 4; ++g) {
      float p0 = __builtin_amdgcn_exp2f(s0[4 * g + 0]);
      float p1 = __builtin_amdgcn_exp2f(s0[4 * g + 1]);
      float p2 = __builtin_amdgcn_exp2f(s0[4 * g + 2]);
      float p3 = __builtin_amdgcn_exp2f(s0[4 * g + 3]);
      psum += (p0 + p1) + (p2 + p3);
      pk4[g] = pk_fp8x4(p0, p1, p2, p3);
    }
    #pragma unroll
    for (int g = 0; g < 4; ++g) {
      float p0 = __builtin_amdgcn_exp2f(s1[4 * g + 0]);
      float p1 = __builtin_amdgcn_exp2f(s1[4 * g + 1]);
      float p2 = __builtin_amdgcn_exp2f(s1[4 * g + 2]);
      float p3 = __builtin_amdgcn_exp2f(s1[4 * g + 3]);
      psum += (p0 + p1) + (p2 + p3);
      pk4[4 + g] = pk_fp8x4(p0, p1, p2, p3);
    }
    psum += __shfl_xor(psum, 32);
    lrun += psum;

    #pragma unroll
    for (int s = 0; s < 4; ++s) {
      long va0 = *(const long*)&vsw[l31 * 72 + s * 16 + q1h * 8];
      long va1 = *(const long*)&vsw[(32 + l31) * 72 + s * 16 + q1h * 8];
      unsigned own_lo = pk4[2 * s], own_hi = pk4[2 * s + 1];
      unsigned send = q1h ? own_lo : own_hi;
      unsigned got = (unsigned)__shfl_xor((int)send, 32);
      unsigned lo = q1h ? got : own_lo;
      unsigned hi = q1h ? own_hi : got;
      long pb = mklong(lo, hi);
      o0 = __builtin_amdgcn_mfma_f32_32x32x16_fp8_fp8(va0, pb, o0, 0, 0, 0);
      o1 = __builtin_amdgcn_mfma_f32_32x32x16_fp8_fp8(va1, pb, o1, 0, 0, 0);
    }
  }

  // ---- two-phase parity combine, then bf16 PARTIAL store (no division) ----
  float* obuf = (float*)kvs;
  __syncthreads();
  if (parity == 1) {
    #pragma unroll
    for (int r = 0; r < 16; ++r) {
      int d = (r & 3) + 8 * (r >> 2) + 4 * q1h;
      obuf[strip * 1024 + d * 32 + l31] = o0[r];
    }
    if (q1h == 0) lbuf[strip * 32 + l31] = lrun;
  }
  __syncthreads();
  if (parity == 0) {
    lrun += lbuf[strip * 32 + l31];
    #pragma unroll
    for (int r = 0; r < 16; ++r) {
      int d = (r & 3) + 8 * (r >> 2) + 4 * q1h;
      o0[r] += obuf[strip * 1024 + d * 32 + l31];
    }
  }
  __syncthreads();
  if (parity == 1) {
    #pragma unroll
    for (int r = 0; r < 16; ++r) {
      int d = (r & 3) + 8 * (r >> 2) + 4 * q1h;
      obuf[strip * 1024 + d * 32 + l31] = o1[r];
    }
  }
  __syncthreads();
  if (parity == 0) {
    #pragma unroll
    for (int r = 0; r < 16; ++r) {
      int d = (r & 3) + 8 * (r >> 2) + 4 * q1h;
      o1[r] += obuf[strip * 1024 + d * 32 + l31];
    }
    unsigned short* stw = st + strip * 2304;   // [32 i][72] bf16
    #pragma unroll
    for (int dm = 0; dm < 2; ++dm) {
      #pragma unroll
      for (int g = 0; g < 4; ++g) {
        ushort4 pk;
        float v0 = (dm == 0) ? o0[4 * g + 0] : o1[4 * g + 0];
        float v1 = (dm == 0) ? o0[4 * g + 1] : o1[4 * g + 1];
        float v2 = (dm == 0) ? o0[4 * g + 2] : o1[4 * g + 2];
        float v3 = (dm == 0) ? o0[4 * g + 3] : o1[4 * g + 3];
        pk.x = f2bf(v0); pk.y = f2bf(v1); pk.z = f2bf(v2); pk.w = f2bf(v3);
        *(ushort4*)&stw[l31 * 72 + dm * 32 + g * 8 + q1h * 4] = pk;
      }
    }
    int slot = jhalf * 16 + bh;
    if (q1h == 0) Lp[(size_t)slot * NN_TOK + iw + l31] = lrun;
    unsigned short* __restrict__ Ppg = Pp + (size_t)slot * NN_TOK * DHEAD;
    #pragma unroll
    for (int it = 0; it < 4; ++it) {
      int idx = it * 64 + lane;
      int row = idx >> 3, ch = idx & 7;
      int tok = iw + row;
      *(uint4*)&Ppg[(size_t)tok * DHEAD + ch * 8] =
          *(const uint4*)&stw[row * 72 + ch * 8];
    }
  }
}

// ---------------------------------------------------------------------------
// Combine: aoT8[b][tok][h*64+d] = fp8( (PpA + PpB) / (lA + lB) ).
// grid (64, 16), 256 thr.
// ---------------------------------------------------------------------------
__global__ __launch_bounds__(256) void attn_combine_kernel(
    const unsigned short* __restrict__ Pp, const float* __restrict__ Lp,
    unsigned char* __restrict__ aoT8) {
  int bh = blockIdx.y;
  int b = bh >> 3, h = bh & 7;
  int t0 = blockIdx.x * 64;
  int t = threadIdx.x;
  const unsigned short* __restrict__ A = Pp + (size_t)bh * NN_TOK * DHEAD;
  const unsigned short* __restrict__ B = Pp + (size_t)(16 + bh) * NN_TOK * DHEAD;
  const float* __restrict__ la = Lp + (size_t)bh * NN_TOK;
  const float* __restrict__ lb = Lp + (size_t)(16 + bh) * NN_TOK;
  #pragma unroll
  for (int it = 0; it < 2; ++it) {
    int f = t + it * 256;          // 0..511
    int row = f >> 3, ch = f & 7;  // tok-local, 8-d chunk
    int tok = t0 + row;
    float inv = 1.0f / (la[tok] + lb[tok]);
    uint4 av = *(const uint4*)&A[(size_t)tok * DHEAD + ch * 8];
    uint4 bv = *(const uint4*)&B[(size_t)tok * DHEAD + ch * 8];
    const unsigned short* ap = (const unsigned short*)&av;
    const unsigned short* bp = (const unsigned short*)&bv;
    float o[8];
    #pragma unroll
    for (int j = 0; j < 8; ++j) o[j] = (bf2f(ap[j]) + bf2f(bp[j])) * inv;
    unsigned lo = pk_fp8x4(o[0], o[1], o[2], o[3]);
    unsigned hi = pk_fp8x4(o[4], o[5], o[6], o[7]);
    *(uint2*)&aoT8[((size_t)(b * NN_TOK + tok)) * HID + h * DHEAD + ch * 8] =
        make_uint2(lo, hi);
  }
}

// ---------------------------------------------------------------------------
extern "C" void kernel_launch(void* const* d_in, const int* in_sizes, int n_in,
                              void* d_out, int out_size, void* d_ws, size_t ws_size,
                              hipStream_t stream) {
  const float* x     = (const float*)d_in[0];
  const float* gamma = (const float*)d_in[1];
  const float* beta  = (const float*)d_in[2];
  const float* wq    = (const float*)d_in[3];
  const float* bq    = (const float*)d_in[4];
  const float* wk    = (const float*)d_in[5];
  const float* bk    = (const float*)d_in[6];
  const float* wv    = (const float*)d_in[7];
  const float* bv    = (const float*)d_in[8];
  const float* wo    = (const float*)d_in[9];
  const float* bo    = (const float*)d_in[10];
  float* out = (float*)d_out;

  const size_t SZ = (size_t)BB * CC * NN_TOK;       // 4,194,304 elements
  const size_t WZ = (size_t)CC * HID;
  unsigned short* xnT = (unsigned short*)d_ws;      // bf16 [b][tok][c]    8 MB
  unsigned char*  qT8 = (unsigned char*)(xnT + SZ); // fp8                 4 MB
  unsigned char*  kT8 = qT8 + SZ;                   // fp8                 4 MB
  unsigned char*  vB8 = kT8 + SZ;                   // fp8 [b][c][tok]     4 MB
  unsigned char*  aoT8 = vB8 + SZ;                  // fp8 [b][tok][hid]   4 MB
  unsigned short* wqb = (unsigned short*)(aoT8 + SZ);
  unsigned short* wkb = wqb + WZ;
  unsigned short* wvb = wkb + WZ;
  unsigned char*  wo8 = (unsigned char*)(wvb + WZ); // fp8 (x16)         0.25 MB
  float2* gnpart = (float2*)(wo8 + WZ);             // 256 float2
  unsigned short* Pp = (unsigned short*)(gnpart + 256);  // 32 x 4096 x 64 bf16  33.6 MB
  float* Lp = (float*)(Pp + (size_t)32 * NN_TOK * DHEAD); // 32 x 4096 f32  0.5 MB

  gn_stats_wconv_kernel<<<dim3(256), dim3(256), 0, stream>>>(
      x, gnpart, wq, wk, wv, wo, wqb, wkb, wvb, wo8);

  gn_norm_t_kernel<<<dim3(NN_TOK / 64, CC / 64, BB), dim3(256), 0, stream>>>(
      x, gamma, beta, gnpart, xnT);

  qkv_gemm_kernel<<<dim3(NN_TOK / 128, 12, BB), dim3(256), 0, stream>>>(
      xnT, wqb, wkb, wvb, bq, bk, bv, qT8, kT8, vB8);

  attn_mfma_kernel<<<dim3(NN_TOK / 128, BB * HEADS * 2), dim3(512), 0, stream>>>(
      qT8, kT8, vB8, Pp, Lp);

  attn_combine_kernel<<<dim3(NN_TOK / 64, BB * HEADS), dim3(256), 0, stream>>>(
      Pp, Lp, aoT8);

  outproj_kernel<<<dim3(NN_TOK / 64, CC / 128, BB), dim3(256), 0, stream>>>(
      aoT8, wo8, bo, x, out);
}

// Round 15
// 186.775 us; speedup vs baseline: 1.1012x; 1.1012x over previous
//
#include <hip/hip_runtime.h>
#include <math.h>

#define BB      2
#define CC      512
#define NN_TOK  4096
#define HEADS   8
#define DHEAD   64
#define HID     512
#define GROUPS  32
#define CPG     (CC / GROUPS)
#define EPS     1e-5f

typedef __bf16 bf16x8 __attribute__((ext_vector_type(8)));
typedef float  f32x4  __attribute__((ext_vector_type(4)));
typedef float  f32x16 __attribute__((ext_vector_type(16)));

static __device__ __forceinline__ unsigned short f2bf(float f) {
  __bf16 h = (__bf16)f;
  return __builtin_bit_cast(unsigned short, h);
}
static __device__ __forceinline__ float bf2f(unsigned short u) {
  unsigned v = (unsigned)u << 16;
  return __builtin_bit_cast(float, v);
}
static __device__ __forceinline__ unsigned pk_fp8x4(float a, float b, float c, float d) {
  int lo = __builtin_amdgcn_cvt_pk_fp8_f32(a, b, 0, false);
  return (unsigned)__builtin_amdgcn_cvt_pk_fp8_f32(c, d, lo, true);
}
static __device__ __forceinline__ unsigned char f2fp8(float a) {
  return (unsigned char)(__builtin_amdgcn_cvt_pk_fp8_f32(a, a, 0, false) & 0xff);
}
static __device__ __forceinline__ long mklong(unsigned lo, unsigned hi) {
  return (long)(((unsigned long long)hi << 32) | lo);
}
#define QKV_WS 32.0f        // wq/wk/wv pre-scale before fp8
#define QKV_WS_INV 0.03125f
#define WO_WS 16.0f         // wo pre-scale before fp8
#define WO_WS_INV 0.0625f

// ---------------------------------------------------------------------------
// GroupNorm stats (one block per quarter-group, grid 256) + fused weight
// conversion: all four 512x512 weights -> fp8 (wq/wk/wv x32, wo x16).
// Each block converts 4096 elements of the 1M-element concat space.
// ---------------------------------------------------------------------------
__global__ __launch_bounds__(256) void gn_stats_wconv_kernel(
    const float* __restrict__ x, float2* __restrict__ part,
    const float* __restrict__ wq, const float* __restrict__ wk,
    const float* __restrict__ wv, const float* __restrict__ wo,
    unsigned char* __restrict__ wq8, unsigned char* __restrict__ wk8,
    unsigned char* __restrict__ wv8, unsigned char* __restrict__ wo8) {
  int blk = blockIdx.x;
  int t = threadIdx.x;
  {
    int wsel = blk >> 6;                       // 64 blocks per weight
    int off = (blk & 63) * 4096 + t * 16;
    const float* s = (wsel == 0) ? wq : (wsel == 1) ? wk : (wsel == 2) ? wv : wo;
    unsigned char* d = (wsel == 0) ? wq8 : (wsel == 1) ? wk8 : (wsel == 2) ? wv8 : wo8;
    float sc = (wsel < 3) ? QKV_WS : WO_WS;
    #pragma unroll
    for (int i = 0; i < 4; ++i) {
      float4 a = *(const float4*)&s[off + i * 4];
      *(unsigned*)&d[off + i * 4] =
          pk_fp8x4(a.x * sc, a.y * sc, a.z * sc, a.w * sc);
    }
  }
  const float4* __restrict__ x4 = (const float4*)(x + (size_t)blk * 16384);
  float s = 0.f, ss = 0.f;
  #pragma unroll
  for (int i = 0; i < 16; ++i) {
    float4 v = x4[t + i * 256];
    s  += v.x + v.y + v.z + v.w;
    ss += v.x * v.x + v.y * v.y + v.z * v.z + v.w * v.w;
  }
  #pragma unroll
  for (int off = 32; off >= 1; off >>= 1) {
    s  += __shfl_down(s, off, 64);
    ss += __shfl_down(ss, off, 64);
  }
  __shared__ float rs[4], rss[4];
  int wid = t >> 6, lane = t & 63;
  if (lane == 0) { rs[wid] = s; rss[wid] = ss; }
  __syncthreads();
  if (t == 0) {
    float2 o;
    o.x = rs[0] + rs[1] + rs[2] + rs[3];
    o.y = rss[0] + rss[1] + rss[2] + rss[3];
    part[blk] = o;
  }
}

// ---------------------------------------------------------------------------
// Fused GroupNorm-apply + transpose: x fp32 [b][c][tok] -> xnT8 fp8 [b][tok][c].
// ---------------------------------------------------------------------------
__global__ __launch_bounds__(256) void gn_norm_t_kernel(
    const float* __restrict__ x, const float* __restrict__ gamma,
    const float* __restrict__ beta, const float2* __restrict__ part,
    unsigned char* __restrict__ xnT8) {
  __shared__ __align__(16) unsigned short lds[64 * 72];
  __shared__ float mu4[4], rs4[4];
  int b = blockIdx.z;
  int t0 = blockIdx.x * 64, c0 = blockIdx.y * 64;
  int t = threadIdx.x;
  if (t < 4) {
    int g = (c0 >> 4) + t;
    int gi = b * GROUPS + g;
    float2 p0 = part[gi * 4 + 0], p1 = part[gi * 4 + 1];
    float2 p2 = part[gi * 4 + 2], p3 = part[gi * 4 + 3];
    float S = p0.x + p1.x + p2.x + p3.x;
    float SS = p0.y + p1.y + p2.y + p3.y;
    const float inv_n = 1.0f / (float)(CPG * NN_TOK);
    float mu = S * inv_n;
    float var = SS * inv_n - mu * mu;
    mu4[t] = mu;
    rs4[t] = rsqrtf(var + EPS);
  }
  __syncthreads();
  const float* __restrict__ xb = x + (size_t)b * CC * NN_TOK;
  #pragma unroll
  for (int i = 0; i < 4; ++i) {
    int f = t + i * 256;
    int row = f >> 4, c16 = f & 15;
    int c = c0 + row;
    float ga = gamma[c] * rs4[row >> 4];
    float be = beta[c] - mu4[row >> 4] * ga;
    float4 v = *(const float4*)&xb[(size_t)c * NN_TOK + t0 + c16 * 4];
    ushort4 pk;
    pk.x = f2bf(v.x * ga + be); pk.y = f2bf(v.y * ga + be);
    pk.z = f2bf(v.z * ga + be); pk.w = f2bf(v.w * ga + be);
    *(ushort4*)&lds[row * 72 + c16 * 4] = pk;
  }
  __syncthreads();
  unsigned char* __restrict__ ob = xnT8 + (size_t)b * NN_TOK * CC;
  #pragma unroll
  for (int i = 0; i < 2; ++i) {
    int f = t + i * 256;
    int row = f >> 3, ch = f & 7;   // row = tok-local, ch = 8-channel chunk
    float v0 = bf2f(lds[(ch * 8 + 0) * 72 + row]);
    float v1 = bf2f(lds[(ch * 8 + 1) * 72 + row]);
    float v2 = bf2f(lds[(ch * 8 + 2) * 72 + row]);
    float v3 = bf2f(lds[(ch * 8 + 3) * 72 + row]);
    float v4 = bf2f(lds[(ch * 8 + 4) * 72 + row]);
    float v5 = bf2f(lds[(ch * 8 + 5) * 72 + row]);
    float v6 = bf2f(lds[(ch * 8 + 6) * 72 + row]);
    float v7 = bf2f(lds[(ch * 8 + 7) * 72 + row]);
    unsigned lo = pk_fp8x4(v0, v1, v2, v3);
    unsigned hi = pk_fp8x4(v4, v5, v6, v7);
    *(uint2*)&ob[(size_t)(t0 + row) * CC + c0 + ch * 8] = make_uint2(lo, hi);
  }
}

// ---------------------------------------------------------------------------
// Fused Q/K/V MFMA GEMM, FULL FP8: xnT8 fp8 B, wq8/wk8/wv8 fp8 A (x32),
// fp8 outputs. Staging 18.4 KB/iter (was 36.9), b64 fragments.
// ---------------------------------------------------------------------------
__global__ __launch_bounds__(256, 3) void qkv_gemm_kernel(
    const unsigned char* __restrict__ xnT8,
    const unsigned char* __restrict__ wq8, const unsigned char* __restrict__ wk8,
    const unsigned char* __restrict__ wv8,
    const float* __restrict__ bq, const float* __restrict__ bk,
    const float* __restrict__ bv,
    unsigned char* __restrict__ qT8, unsigned char* __restrict__ kT8,
    unsigned char* __restrict__ vB8) {
  __shared__ __align__(16) unsigned char As8[128 * 72];
  __shared__ __align__(16) unsigned char Bs8[128 * 72];
  int b = blockIdx.z;
  int y = blockIdx.y;
  int which = y >> 2, yl = y & 3;
  const unsigned char* __restrict__ W =
      (which == 0) ? wq8 : (which == 1) ? wk8 : wv8;
  const float* __restrict__ bias = (which == 0) ? bq : (which == 1) ? bk : bv;
  int m0 = yl * 128;
  int n0 = blockIdx.x * 128;
  const unsigned char* __restrict__ Bsrc = xnT8 + (size_t)b * NN_TOK * CC;
  int t = threadIdx.x, w = t >> 6, lane = t & 63;
  int wm = (w >> 1) * 64, wn = (w & 1) * 64;
  int l15 = lane & 15, lq = lane >> 4;

  f32x4 acc[4][4];
  #pragma unroll
  for (int mt = 0; mt < 4; ++mt)
    #pragma unroll
    for (int nt = 0; nt < 4; ++nt) acc[mt][nt] = (f32x4){0.f, 0.f, 0.f, 0.f};

  for (int kc = 0; kc < CC; kc += 64) {
    __syncthreads();
    #pragma unroll
    for (int i = 0; i < 2; ++i) {
      int idx = t + i * 256;              // 0..511
      int row = idx >> 2, ch = idx & 3;   // 128 rows x 4 16B-chunks
      uint4 a = *(const uint4*)&W[(size_t)(m0 + row) * CC + kc + ch * 16];
      unsigned char* ad = &As8[row * 72 + ch * 16];
      *(uint2*)ad = make_uint2(a.x, a.y);
      *(uint2*)(ad + 8) = make_uint2(a.z, a.w);
      uint4 bb = *(const uint4*)&Bsrc[(size_t)(n0 + row) * CC + kc + ch * 16];
      unsigned char* bd = &Bs8[row * 72 + ch * 16];
      *(uint2*)bd = make_uint2(bb.x, bb.y);
      *(uint2*)(bd + 8) = make_uint2(bb.z, bb.w);
    }
    __syncthreads();
    #pragma unroll
    for (int ks = 0; ks < 2; ++ks) {
      long af[4], bfr[4];
      #pragma unroll
      for (int i = 0; i < 4; ++i) {
        af[i]  = *(const long*)&As8[(wm + i * 16 + l15) * 72 + ks * 32 + lq * 8];
        bfr[i] = *(const long*)&Bs8[(wn + i * 16 + l15) * 72 + ks * 32 + lq * 8];
      }
      #pragma unroll
      for (int mt = 0; mt < 4; ++mt)
        #pragma unroll
        for (int nt = 0; nt < 4; ++nt)
          acc[mt][nt] = __builtin_amdgcn_mfma_f32_16x16x32_fp8_fp8(
              af[mt], bfr[nt], acc[mt][nt], 0, 0, 0);
    }
  }
  __syncthreads();

  if (which < 2) {
    const float sc = (which == 0) ? 0.18033688011112043f : 1.0f; // 0.125*log2e
    unsigned char* __restrict__ dstT = (which == 0) ? qT8 : kT8;
    unsigned char* buf = As8 + w * 2560;   // per-wave [32 tok][80 B]
    int h = (m0 + wm) >> 6;
    const size_t hbase = (size_t)(b * HEADS + h) * NN_TOK;
    #pragma unroll
    for (int p = 0; p < 2; ++p) {
      #pragma unroll
      for (int mt = 0; mt < 4; ++mt) {
        float4 bv4 = *(const float4*)&bias[m0 + wm + mt * 16 + lq * 4];
        #pragma unroll
        for (int ntl = 0; ntl < 2; ++ntl) {
          int nt = p * 2 + ntl;
          f32x4 a = acc[mt][nt];
          unsigned pk = pk_fp8x4((a[0] * QKV_WS_INV + bv4.x) * sc,
                                 (a[1] * QKV_WS_INV + bv4.y) * sc,
                                 (a[2] * QKV_WS_INV + bv4.z) * sc,
                                 (a[3] * QKV_WS_INV + bv4.w) * sc);
          *(unsigned*)&buf[(ntl * 16 + l15) * 80 + mt * 16 + lq * 4] = pk;
        }
      }
      #pragma unroll
      for (int it = 0; it < 2; ++it) {
        int idx = it * 64 + lane;
        int row = idx >> 2, ch = idx & 3;
        int tok = n0 + wn + p * 32 + row;
        *(uint4*)&dstT[(hbase + tok) * DHEAD + ch * 16] =
            *(const uint4*)&buf[row * 80 + ch * 16];
      }
      __syncthreads();
    }
  } else {
    unsigned char* __restrict__ dst = vB8 + (size_t)b * HID * NN_TOK;
    #pragma unroll
    for (int mt = 0; mt < 4; ++mt) {
      float4 bv4 = *(const float4*)&bias[m0 + wm + mt * 16 + lq * 4];
      float bvr[4] = {bv4.x, bv4.y, bv4.z, bv4.w};
      #pragma unroll
      for (int nt = 0; nt < 4; ++nt) {
        int tok = n0 + wn + nt * 16 + l15;
        #pragma unroll
        for (int r = 0; r < 4; ++r) {
          int m = m0 + wm + mt * 16 + lq * 4 + r;
          dst[(size_t)m * NN_TOK + tok] = f2fp8(acc[mt][nt][r] * QKV_WS_INV + bvr[r]);
        }
      }
    }
  }
}

// ---------------------------------------------------------------------------
// Out-proj MFMA GEMM, fp8 inputs (wo8 x16, aoT8 fp8). 128m x 64n, grid (64,4,2).
// ---------------------------------------------------------------------------
__global__ __launch_bounds__(256) void outproj_kernel(
    const unsigned char* __restrict__ aoT8, const unsigned char* __restrict__ wo8,
    const float* __restrict__ bo, const float* __restrict__ x,
    float* __restrict__ out) {
  __shared__ __align__(16) unsigned char As8[128 * 80];
  __shared__ __align__(16) unsigned char Bs8[64 * 80];
  int b = blockIdx.z;
  int m0 = blockIdx.y * 128;
  int n0 = blockIdx.x * 64;
  const unsigned char* __restrict__ Bsrc = aoT8 + (size_t)b * NN_TOK * HID;
  int t = threadIdx.x, w = t >> 6, lane = t & 63;
  int wm = (w & 1) * 64, wn = (w >> 1) * 32;
  int l15 = lane & 15, lq = lane >> 4;

  f32x4 acc[4][2];
  #pragma unroll
  for (int mt = 0; mt < 4; ++mt)
    #pragma unroll
    for (int nt = 0; nt < 2; ++nt) acc[mt][nt] = (f32x4){0.f, 0.f, 0.f, 0.f};

  for (int kc = 0; kc < HID; kc += 64) {
    __syncthreads();
    #pragma unroll
    for (int i = 0; i < 2; ++i) {
      int f = t + i * 256;
      int row = f >> 2, ch = f & 3;
      *(uint4*)&As8[row * 80 + ch * 16] =
          *(const uint4*)&wo8[(size_t)(m0 + row) * HID + kc + ch * 16];
    }
    {
      int row = t >> 2, ch = t & 3;
      *(uint4*)&Bs8[row * 80 + ch * 16] =
          *(const uint4*)&Bsrc[(size_t)(n0 + row) * HID + kc + ch * 16];
    }
    __syncthreads();
    #pragma unroll
    for (int ks = 0; ks < 2; ++ks) {
      long af[4], bfr[2];
      #pragma unroll
      for (int i = 0; i < 4; ++i)
        af[i] = *(const long*)&As8[(wm + i * 16 + l15) * 80 + ks * 32 + lq * 8];
      #pragma unroll
      for (int i = 0; i < 2; ++i)
        bfr[i] = *(const long*)&Bs8[(wn + i * 16 + l15) * 80 + ks * 32 + lq * 8];
      #pragma unroll
      for (int mt = 0; mt < 4; ++mt)
        #pragma unroll
        for (int nt = 0; nt < 2; ++nt)
          acc[mt][nt] = __builtin_amdgcn_mfma_f32_16x16x32_fp8_fp8(
              af[mt], bfr[nt], acc[mt][nt], 0, 0, 0);
    }
  }

  const float* __restrict__ xb = x + (size_t)b * CC * NN_TOK;
  float* __restrict__ ob = out + (size_t)b * CC * NN_TOK;
  #pragma unroll
  for (int mt = 0; mt < 4; ++mt) {
    float4 bv4 = *(const float4*)&bo[m0 + wm + mt * 16 + lq * 4];
    float bvr[4] = {bv4.x, bv4.y, bv4.z, bv4.w};
    #pragma unroll
    for (int nt = 0; nt < 2; ++nt) {
      int tok = n0 + wn + nt * 16 + l15;
      #pragma unroll
      for (int r = 0; r < 4; ++r) {
        int m = m0 + wm + mt * 16 + lq * 4 + r;
        size_t off = (size_t)m * NN_TOK + tok;
        ob[off] = acc[mt][nt][r] * WO_WS_INV + bvr[r] + xb[off];
      }
    }
  }
}

// ---------------------------------------------------------------------------
// MFMA flash attention, round 15: r13 fp8 core (grid (32,16), 4 i-strips x
// 2 j-parities) + ONES-TRICK: l computed by a 3rd MFMA chain with A=all-ones
// fp8 (every C row = sum_j P[j][i]), deleting 32 VALU adds + 1 shfl per iter
// and making l exactly consistent with the fp8 P used in PV. Epilogue emits
// fp8 aoT directly.
// ---------------------------------------------------------------------------
__global__ __launch_bounds__(512, 4) void attn_mfma_kernel(
    const unsigned char* __restrict__ qT8, const unsigned char* __restrict__ kT8,
    const unsigned char* __restrict__ vv8, unsigned char* __restrict__ aoT8) {
  __shared__ __align__(16) unsigned char kvs[4 * 4608];   // 2 K + 2 V fp8 tiles
  __shared__ __align__(16) unsigned char st8[4 * 32 * 80]; // epilogue stage fp8
  __shared__ float lbuf[128];
  unsigned char* ks8 = kvs;
  unsigned char* vs8 = kvs + 2 * 4608;
  int bh = blockIdx.y;
  int b = bh >> 3, h = bh & 7;
  int i0 = blockIdx.x * 128;
  const size_t hb = (size_t)bh * NN_TOK;
  const unsigned char* __restrict__ qtg = qT8 + hb * DHEAD;
  const unsigned char* __restrict__ ktg = kT8 + hb * DHEAD;
  const unsigned char* __restrict__ vg  = vv8 + hb * DHEAD;
  int t = threadIdx.x;
  int w = t >> 6, lane = t & 63, l31 = lane & 31, q1h = lane >> 5;
  int strip = w & 3, parity = w >> 2;
  int iw = i0 + strip * 32;
  const long ones8 = 0x3838383838383838LL;   // 8x fp8 e4m3 1.0

  const unsigned char* qrow = qtg + (size_t)(iw + l31) * DHEAD;
  uint4 qv0 = *(const uint4*)(qrow);
  uint4 qv1 = *(const uint4*)(qrow + 16);
  uint4 qv2 = *(const uint4*)(qrow + 32);
  uint4 qv3 = *(const uint4*)(qrow + 48);
  long qf[4];
  qf[0] = q1h ? mklong(qv0.z, qv0.w) : mklong(qv0.x, qv0.y);
  qf[1] = q1h ? mklong(qv1.z, qv1.w) : mklong(qv1.x, qv1.y);
  qf[2] = q1h ? mklong(qv2.z, qv2.w) : mklong(qv2.x, qv2.y);
  qf[3] = q1h ? mklong(qv3.z, qv3.w) : mklong(qv3.x, qv3.y);

  f32x16 o0 = {0,0,0,0,0,0,0,0,0,0,0,0,0,0,0,0};
  f32x16 o1 = {0,0,0,0,0,0,0,0,0,0,0,0,0,0,0,0};
  f32x16 lacc = {0,0,0,0,0,0,0,0,0,0,0,0,0,0,0,0};
  const unsigned char* __restrict__ ksw = ks8 + parity * 4608;
  const unsigned char* __restrict__ vsw = vs8 + parity * 4608;

  for (int rt = 0; rt < NN_TOK / 128; ++rt) {
    int j0 = rt * 128;
    __syncthreads();
    {
      int jr = t >> 2, ch = t & 3;
      int ktile = jr >> 6, krow = jr & 63;
      uint4 kx = *(const uint4*)&ktg[(size_t)(j0 + jr) * DHEAD + ch * 16];
      unsigned char* kd = &ks8[ktile * 4608 + krow * 72 + ch * 16];
      *(uint2*)kd = make_uint2(kx.x, kx.y);
      *(uint2*)(kd + 8) = make_uint2(kx.z, kx.w);
      int vtile = t >> 8, vrr = (t >> 2) & 63, vch = t & 3;
      uint4 vx = *(const uint4*)&vg[(size_t)vrr * NN_TOK + j0 + vtile * 64 + vch * 16];
      unsigned char* vd = &vs8[vtile * 4608 + vrr * 72 + vch * 16];
      *(uint2*)vd = make_uint2(vx.x, vx.y);
      *(uint2*)(vd + 8) = make_uint2(vx.z, vx.w);
    }
    __syncthreads();

    f32x16 s0 = {0,0,0,0,0,0,0,0,0,0,0,0,0,0,0,0};
    f32x16 s1 = {0,0,0,0,0,0,0,0,0,0,0,0,0,0,0,0};
    #pragma unroll
    for (int s = 0; s < 4; ++s) {
      long a0 = *(const long*)&ksw[l31 * 72 + s * 16 + q1h * 8];
      long a1 = *(const long*)&ksw[(32 + l31) * 72 + s * 16 + q1h * 8];
      s0 = __builtin_amdgcn_mfma_f32_32x32x16_fp8_fp8(a0, qf[s], s0, 0, 0, 0);
      s1 = __builtin_amdgcn_mfma_f32_32x32x16_fp8_fp8(a1, qf[s], s1, 0, 0, 0);
    }

    // exp2 (no shift), pack 4 fp8 per dword; l handled by ones-MFMA below
    unsigned pk4[8];
    #pragma unroll
    for (int g = 0; g < 4; ++g) {
      float p0 = __builtin_amdgcn_exp2f(s0[4 * g + 0]);
      float p1 = __builtin_amdgcn_exp2f(s0[4 * g + 1]);
      float p2 = __builtin_amdgcn_exp2f(s0[4 * g + 2]);
      float p3 = __builtin_amdgcn_exp2f(s0[4 * g + 3]);
      pk4[g] = pk_fp8x4(p0, p1, p2, p3);
    }
    #pragma unroll
    for (int g = 0; g < 4; ++g) {
      float p0 = __builtin_amdgcn_exp2f(s1[4 * g + 0]);
      float p1 = __builtin_amdgcn_exp2f(s1[4 * g + 1]);
      float p2 = __builtin_amdgcn_exp2f(s1[4 * g + 2]);
      float p3 = __builtin_amdgcn_exp2f(s1[4 * g + 3]);
      pk4[4 + g] = pk_fp8x4(p0, p1, p2, p3);
    }

    #pragma unroll
    for (int s = 0; s < 4; ++s) {
      long va0 = *(const long*)&vsw[l31 * 72 + s * 16 + q1h * 8];
      long va1 = *(const long*)&vsw[(32 + l31) * 72 + s * 16 + q1h * 8];
      unsigned own_lo = pk4[2 * s], own_hi = pk4[2 * s + 1];
      unsigned send = q1h ? own_lo : own_hi;
      unsigned got = (unsigned)__shfl_xor((int)send, 32);
      unsigned lo = q1h ? got : own_lo;
      unsigned hi = q1h ? own_hi : got;
      long pb = mklong(lo, hi);
      o0 = __builtin_amdgcn_mfma_f32_32x32x16_fp8_fp8(va0, pb, o0, 0, 0, 0);
      o1 = __builtin_amdgcn_mfma_f32_32x32x16_fp8_fp8(va1, pb, o1, 0, 0, 0);
      lacc = __builtin_amdgcn_mfma_f32_32x32x16_fp8_fp8(ones8, pb, lacc, 0, 0, 0);
    }
  }
  float lrun = lacc[0];   // all 32 C-rows equal sum_j P[j][i]

  // ---- two-phase parity combine (obuf overlays staging; st8 separate) ----
  float* obuf = (float*)kvs;           // [strip][d 32][i 32] f32 = 16 KB
  __syncthreads();
  if (parity == 1) {                   // phase A: o0 (d 0..31)
    #pragma unroll
    for (int r = 0; r < 16; ++r) {
      int d = (r & 3) + 8 * (r >> 2) + 4 * q1h;
      obuf[strip * 1024 + d * 32 + l31] = o0[r];
    }
    if (q1h == 0) lbuf[strip * 32 + l31] = lrun;
  }
  __syncthreads();
  if (parity == 0) {
    lrun += lbuf[strip * 32 + l31];
    #pragma unroll
    for (int r = 0; r < 16; ++r) {
      int d = (r & 3) + 8 * (r >> 2) + 4 * q1h;
      o0[r] += obuf[strip * 1024 + d * 32 + l31];
    }
  }
  __syncthreads();
  if (parity == 1) {                   // phase B: o1 (d 32..63)
    #pragma unroll
    for (int r = 0; r < 16; ++r) {
      int d = (r & 3) + 8 * (r >> 2) + 4 * q1h;
      obuf[strip * 1024 + d * 32 + l31] = o1[r];
    }
  }
  __syncthreads();
  if (parity == 0) {
    #pragma unroll
    for (int r = 0; r < 16; ++r) {
      int d = (r & 3) + 8 * (r >> 2) + 4 * q1h;
      o1[r] += obuf[strip * 1024 + d * 32 + l31];
    }
    float inv = 1.0f / lrun;
    unsigned char* stw = st8 + strip * 2560;   // [32 i][80 B]
    #pragma unroll
    for (int dm = 0; dm < 2; ++dm) {
      #pragma unroll
      for (int g = 0; g < 4; ++g) {
        float v0 = ((dm == 0) ? o0[4 * g + 0] : o1[4 * g + 0]) * inv;
        float v1 = ((dm == 0) ? o0[4 * g + 1] : o1[4 * g + 1]) * inv;
        float v2 = ((dm == 0) ? o0[4 * g + 2] : o1[4 * g + 2]) * inv;
        float v3 = ((dm == 0) ? o0[4 * g + 3] : o1[4 * g + 3]) * inv;
        *(unsigned*)&stw[l31 * 80 + dm * 32 + g * 8 + q1h * 4] =
            pk_fp8x4(v0, v1, v2, v3);
      }
    }
    const size_t obase = (size_t)b * NN_TOK;
    #pragma unroll
    for (int it = 0; it < 4; ++it) {
      int idx = it * 64 + lane;
      int row = idx >> 3, ch = idx & 7;      // 32 rows x 8 8B-chunks
      int tok = iw + row;
      *(uint2*)&aoT8[(obase + tok) * HID + h * DHEAD + ch * 8] =
          *(const uint2*)&stw[row * 80 + ch * 8];
    }
  }
}

// ---------------------------------------------------------------------------
extern "C" void kernel_launch(void* const* d_in, const int* in_sizes, int n_in,
                              void* d_out, int out_size, void* d_ws, size_t ws_size,
                              hipStream_t stream) {
  const float* x     = (const float*)d_in[0];
  const float* gamma = (const float*)d_in[1];
  const float* beta  = (const float*)d_in[2];
  const float* wq    = (const float*)d_in[3];
  const float* bq    = (const float*)d_in[4];
  const float* wk    = (const float*)d_in[5];
  const float* bk    = (const float*)d_in[6];
  const float* wv    = (const float*)d_in[7];
  const float* bv    = (const float*)d_in[8];
  const float* wo    = (const float*)d_in[9];
  const float* bo    = (const float*)d_in[10];
  float* out = (float*)d_out;

  const size_t SZ = (size_t)BB * CC * NN_TOK;       // 4,194,304 elements
  const size_t WZ = (size_t)CC * HID;
  unsigned char* xnT8 = (unsigned char*)d_ws;       // fp8 [b][tok][c]     4 MB
  unsigned char* qT8  = xnT8 + SZ;                  // fp8 [b,h,tok,d]     4 MB
  unsigned char* kT8  = qT8 + SZ;                   // fp8                 4 MB
  unsigned char* vB8  = kT8 + SZ;                   // fp8 [b][c][tok]     4 MB
  unsigned char* aoT8 = vB8 + SZ;                   // fp8 [b][tok][hid]   4 MB
  unsigned char* wq8  = aoT8 + SZ;                  // fp8 weights (x32)
  unsigned char* wk8  = wq8 + WZ;
  unsigned char* wv8  = wk8 + WZ;
  unsigned char* wo8  = wv8 + WZ;                   // fp8 (x16)
  float2* gnpart = (float2*)(wo8 + WZ);             // 256 float2

  gn_stats_wconv_kernel<<<dim3(256), dim3(256), 0, stream>>>(
      x, gnpart, wq, wk, wv, wo, wq8, wk8, wv8, wo8);

  gn_norm_t_kernel<<<dim3(NN_TOK / 64, CC / 64, BB), dim3(256), 0, stream>>>(
      x, gamma, beta, gnpart, xnT8);

  qkv_gemm_kernel<<<dim3(NN_TOK / 128, 12, BB), dim3(256), 0, stream>>>(
      xnT8, wq8, wk8, wv8, bq, bk, bv, qT8, kT8, vB8);

  attn_mfma_kernel<<<dim3(NN_TOK / 128, BB * HEADS), dim3(512), 0, stream>>>(
      qT8, kT8, vB8, aoT8);

  outproj_kernel<<<dim3(NN_TOK / 64, CC / 128, BB), dim3(256), 0, stream>>>(
      aoT8, wo8, bo, x, out);
}